// Round 6
// baseline (1282.289 us; speedup 1.0000x reference)
//
#include <hip/hip_runtime.h>
#include <hip/hip_bf16.h>

typedef __bf16 bf16;

// B=2, T=512, C=8, D=512, H=8, dk=64. M = B*T*C = 8192 rows.
// Inputs fp32, dict order. OUTPUT fp32 (reference returns float32 — this was
// the bug through round 5: writing bf16 into an fp32-validated buffer).
// ws: Q | K | V (each 8192*512 bf16 = 8.39MB), layout [hd][t][d],
// hd = b*64 + h*8 + c. X staged fp32 in-place in d_out.

// ---------------- QKV projection: grid (512, 3), block 256 -------------------
__global__ __launch_bounds__(256) void qkv_kernel(
    const float* __restrict__ qin, const float* __restrict__ kin,
    const float* __restrict__ vin,
    const float* __restrict__ Wq, const float* __restrict__ Bq,
    const float* __restrict__ Wk, const float* __restrict__ Bk,
    const float* __restrict__ Wv, const float* __restrict__ Bv,
    bf16* __restrict__ Qws, bf16* __restrict__ Kws, bf16* __restrict__ Vws)
{
    __shared__ float Xs[16][512];
    const int tid = threadIdx.x;
    const int r0  = blockIdx.x * 16;
    const int z   = blockIdx.y;
    const float *X, *W, *Bi; bf16* O;
    if (z == 0)      { X = qin; W = Wq; Bi = Bq; O = Qws; }
    else if (z == 1) { X = kin; W = Wk; Bi = Bk; O = Kws; }
    else             { X = vin; W = Wv; Bi = Bv; O = Vws; }

    for (int i = tid; i < 16 * 512; i += 256)
        Xs[i >> 9][i & 511] = X[(size_t)(r0 + (i >> 9)) * 512 + (i & 511)];
    __syncthreads();

    float acc0[16], acc1[16];
    #pragma unroll
    for (int r = 0; r < 16; r++) { acc0[r] = 0.f; acc1[r] = 0.f; }
    const int c0 = tid, c1 = 256 + tid;
    for (int k = 0; k < 512; k++) {
        const float w0 = W[(size_t)k * 512 + c0];
        const float w1 = W[(size_t)k * 512 + c1];
        #pragma unroll
        for (int r = 0; r < 16; r++) {
            const float x = Xs[r][k];
            acc0[r] += x * w0;
            acc1[r] += x * w1;
        }
    }
    const float b0 = Bi[c0], b1 = Bi[c1];
    #pragma unroll
    for (int r = 0; r < 16; r++) {
        const int rowg = r0 + r;
        const int b = rowg >> 12, t = (rowg >> 3) & 511, c = rowg & 7;
        {
            const int hd = b * 64 + (c0 >> 6) * 8 + c;
            O[((size_t)hd * 512 + t) * 64 + (c0 & 63)] = (bf16)(acc0[r] + b0);
        }
        {
            const int hd = b * 64 + (c1 >> 6) * 8 + c;
            O[((size_t)hd * 512 + t) * 64 + (c1 & 63)] = (bf16)(acc1[r] + b1);
        }
    }
}

// ---------------- attention: grid (512, 128), block 256 ----------------------
__global__ __launch_bounds__(256) void attn_kernel(
    const bf16* __restrict__ Qws, const bf16* __restrict__ Kws,
    const bf16* __restrict__ Vws, const int* __restrict__ mask,
    float* __restrict__ Xout)
{
    __shared__ float Qf[64];
    __shared__ float Pf[512];
    __shared__ float red1[4];
    __shared__ float red2[4];
    __shared__ float Opart[4][64];
    const int tid = threadIdx.x;
    const int q   = blockIdx.x;
    const int hd  = blockIdx.y;
    const int b = hd >> 6, h = (hd >> 3) & 7, c = hd & 7;
    const bf16* Qh = Qws + (size_t)hd * 512 * 64;
    const bf16* Kh = Kws + (size_t)hd * 512 * 64;
    const bf16* Vh = Vws + (size_t)hd * 512 * 64;

    if (tid < 64) Qf[tid] = (float)Qh[(size_t)q * 64 + tid];
    __syncthreads();

    const int* mrow = mask + ((size_t)b * 512 + q) * 512;
    const int s0 = tid * 2, s1 = tid * 2 + 1;
    float a0 = 0.f, a1 = 0.f;
    for (int d = 0; d < 64; d++) {
        const float qd = Qf[d];
        a0 += qd * (float)Kh[(size_t)s0 * 64 + d];
        a1 += qd * (float)Kh[(size_t)s1 * 64 + d];
    }
    a0 *= 0.125f; a1 *= 0.125f;
    if (mrow[s0] == 0) a0 = -1.0e9f;
    if (mrow[s1] == 0) a1 = -1.0e9f;

    float mx = fmaxf(a0, a1);
    #pragma unroll
    for (int off = 1; off < 64; off <<= 1) mx = fmaxf(mx, __shfl_xor(mx, off, 64));
    if ((tid & 63) == 0) red1[tid >> 6] = mx;
    __syncthreads();
    mx = fmaxf(fmaxf(red1[0], red1[1]), fmaxf(red1[2], red1[3]));

    const float e0 = __expf(a0 - mx), e1 = __expf(a1 - mx);
    Pf[s0] = e0; Pf[s1] = e1;
    float sm = e0 + e1;
    #pragma unroll
    for (int off = 1; off < 64; off <<= 1) sm += __shfl_xor(sm, off, 64);
    if ((tid & 63) == 0) red2[tid >> 6] = sm;
    __syncthreads();
    sm = red2[0] + red2[1] + red2[2] + red2[3];
    const float inv = 1.f / sm;

    const int d = tid & 63, sg = tid >> 6;
    float oa = 0.f;
    for (int s = sg * 128; s < sg * 128 + 128; s++)
        oa += Pf[s] * (float)Vh[(size_t)s * 64 + d];
    Opart[sg][d] = oa;
    __syncthreads();
    if (tid < 64) {
        const float o = (Opart[0][tid] + Opart[1][tid] +
                         Opart[2][tid] + Opart[3][tid]) * inv;
        const size_t row = ((size_t)b * 512 + q) * 8 + c;
        Xout[row * 512 + h * 64 + tid] = o;
    }
}

// ---------------- output projection, in place on d_out (fp32) ----------------
__global__ __launch_bounds__(256) void out_kernel(
    const float* __restrict__ Wo, const float* __restrict__ Bo,
    float* __restrict__ out)
{
    __shared__ float Xs[16][512];
    const int tid = threadIdx.x;
    const int r0  = blockIdx.x * 16;
    for (int i = tid; i < 16 * 512; i += 256)
        Xs[i >> 9][i & 511] = out[(size_t)(r0 + (i >> 9)) * 512 + (i & 511)];
    __syncthreads();

    float acc0[16], acc1[16];
    #pragma unroll
    for (int r = 0; r < 16; r++) { acc0[r] = 0.f; acc1[r] = 0.f; }
    const int c0 = tid, c1 = 256 + tid;
    for (int k = 0; k < 512; k++) {
        const float w0 = Wo[(size_t)k * 512 + c0];
        const float w1 = Wo[(size_t)k * 512 + c1];
        #pragma unroll
        for (int r = 0; r < 16; r++) {
            const float x = Xs[r][k];
            acc0[r] += x * w0;
            acc1[r] += x * w1;
        }
    }
    const float b0 = Bo[c0], b1 = Bo[c1];
    #pragma unroll
    for (int r = 0; r < 16; r++) {
        out[(size_t)(r0 + r) * 512 + c0] = acc0[r] + b0;
        out[(size_t)(r0 + r) * 512 + c1] = acc1[r] + b1;
    }
}

extern "C" void kernel_launch(void* const* d_in, const int* in_sizes, int n_in,
                              void* d_out, int out_size, void* d_ws, size_t ws_size,
                              hipStream_t stream)
{
    const float* qin  = (const float*)d_in[0];
    const float* kin  = (const float*)d_in[1];
    const float* vin  = (const float*)d_in[2];
    const int*   mask = (const int*)d_in[3];
    const float* Wq = (const float*)d_in[4];
    const float* Bq = (const float*)d_in[5];
    const float* Wk = (const float*)d_in[6];
    const float* Bk = (const float*)d_in[7];
    const float* Wv = (const float*)d_in[8];
    const float* Bv = (const float*)d_in[9];
    const float* Wo = (const float*)d_in[10];
    const float* Bo = (const float*)d_in[11];
    float* out = (float*)d_out;

    // workspace: Q | K | V, each 8192*512 bf16 (8.39 MB) => 25.2 MB total.
    bf16* Qws = (bf16*)d_ws;
    bf16* Kws = Qws + (size_t)8192 * 512;
    bf16* Vws = Kws + (size_t)8192 * 512;

    qkv_kernel<<<dim3(512, 3), dim3(256), 0, stream>>>(
        qin, kin, vin, Wq, Bq, Wk, Bk, Wv, Bv, Qws, Kws, Vws);
    attn_kernel<<<dim3(512, 128), dim3(256), 0, stream>>>(
        Qws, Kws, Vws, mask, out);
    out_kernel<<<dim3(512), dim3(256), 0, stream>>>(Wo, Bo, out);
}

// Round 7
// 286.761 us; speedup vs baseline: 4.4716x; 4.4716x over previous
//
#include <hip/hip_runtime.h>
#include <hip/hip_bf16.h>

typedef __bf16 bf16;
typedef __bf16 bf16x8 __attribute__((ext_vector_type(8)));
typedef float floatx4 __attribute__((ext_vector_type(4)));

// B=2, T=512, C=8, D=512, H=8, dk=64. M = B*T*C = 8192.
// Inputs fp32 (dict order), output fp32. Intermediates bf16 in ws:
// Q,K layout [hd][t][d]; V^T layout [hd][d][t]; X layout [M][512];
// hd = b*64 + h*8 + c.
#define LDA 40  // LDS row stride (bf16); 80B rows, 16B-aligned

union Pack8 { bf16 h[8]; uint4 u; };

__device__ __forceinline__ Pack8 load8_f32(const float* p) {
    float4 a = *(const float4*)p;
    float4 b = *(const float4*)(p + 4);
    Pack8 r;
    r.h[0] = (bf16)a.x; r.h[1] = (bf16)a.y; r.h[2] = (bf16)a.z; r.h[3] = (bf16)a.w;
    r.h[4] = (bf16)b.x; r.h[5] = (bf16)b.y; r.h[6] = (bf16)b.z; r.h[7] = (bf16)b.w;
    return r;
}
template<typename T> __device__ __forceinline__ Pack8 load8(const T* p);
template<> __device__ __forceinline__ Pack8 load8<float>(const float* p) { return load8_f32(p); }
template<> __device__ __forceinline__ Pack8 load8<bf16>(const bf16* p)  { Pack8 r; r.u = *(const uint4*)p; return r; }

// ---------------- GEMM core: C[64x64] tile = A[64xK] @ W[Kx64], K=512 ---------
template<typename TA, typename TW>
__device__ __forceinline__ void gemm_tile(
    const TA* __restrict__ A, const TW* __restrict__ W,
    bf16 (*Asm)[LDA], bf16 (*Bsm)[LDA],
    floatx4 acc[2][2], int mblk, int nblk)
{
    const int tid  = threadIdx.x;
    const int lane = tid & 63;
    const int wave = tid >> 6;
    const int quad = lane >> 4;
    const int l16  = lane & 15;
    const int wrow = (wave >> 1) * 32;
    const int wcol = (wave & 1) * 32;
    const int ar = tid >> 2;          // 0..63
    const int ac = (tid & 3) * 8;     // 0,8,16,24
    const int bk = tid >> 3;          // 0..31
    const int bc = (tid & 7) * 8;     // 0..56
    const int rot = tid & 7;

    for (int k0 = 0; k0 < 512; k0 += 32) {
        Pack8 av = load8(A + (size_t)(mblk + ar) * 512 + k0 + ac);
        Pack8 bv = load8(W + (size_t)(k0 + bk) * 512 + nblk + bc);
        __syncthreads();  // prior iter's LDS reads done
        *(uint4*)(&Asm[ar][ac]) = av.u;
        #pragma unroll
        for (int j = 0; j < 8; j++) {
            int jj = (j + rot) & 7;
            Bsm[bc + jj][bk] = bv.h[jj];
        }
        __syncthreads();
        bf16x8 af0 = *(const bf16x8*)(&Asm[wrow + l16][quad * 8]);
        bf16x8 af1 = *(const bf16x8*)(&Asm[wrow + 16 + l16][quad * 8]);
        bf16x8 bf0 = *(const bf16x8*)(&Bsm[wcol + l16][quad * 8]);
        bf16x8 bf1 = *(const bf16x8*)(&Bsm[wcol + 16 + l16][quad * 8]);
        acc[0][0] = __builtin_amdgcn_mfma_f32_16x16x32_bf16(af0, bf0, acc[0][0], 0, 0, 0);
        acc[0][1] = __builtin_amdgcn_mfma_f32_16x16x32_bf16(af0, bf1, acc[0][1], 0, 0, 0);
        acc[1][0] = __builtin_amdgcn_mfma_f32_16x16x32_bf16(af1, bf0, acc[1][0], 0, 0, 0);
        acc[1][1] = __builtin_amdgcn_mfma_f32_16x16x32_bf16(af1, bf1, acc[1][1], 0, 0, 0);
    }
}

// LAYOUT 0: bf16 per-head [hd][t][d] (Q,K). LAYOUT 1: bf16 [hd][d][t] (V^T).
// LAYOUT 2: fp32 row-major (final output).
template<int LAYOUT, typename TO>
__device__ __forceinline__ void gemm_epilogue(
    const float* __restrict__ bias, TO* __restrict__ out,
    floatx4 acc[2][2], int mblk, int nblk)
{
    const int lane = threadIdx.x & 63;
    const int wave = threadIdx.x >> 6;
    const int quad = lane >> 4;
    const int l16  = lane & 15;
    const int wrow = (wave >> 1) * 32;
    const int wcol = (wave & 1) * 32;
    #pragma unroll
    for (int i = 0; i < 2; i++) {
        #pragma unroll
        for (int j = 0; j < 2; j++) {
            const int colg = nblk + wcol + j * 16 + l16;
            const float bb = bias[colg];
            #pragma unroll
            for (int r = 0; r < 4; r++) {
                const int rowg = mblk + wrow + i * 16 + quad * 4 + r;
                float v = acc[i][j][r] + bb;
                size_t addr;
                if (LAYOUT == 2) {
                    addr = (size_t)rowg * 512 + colg;
                } else {
                    const int b = rowg >> 12;
                    const int t = (rowg >> 3) & 511;
                    const int c = rowg & 7;
                    const int h = colg >> 6;
                    const int d = colg & 63;
                    const int hd = b * 64 + h * 8 + c;
                    if (LAYOUT == 0) addr = ((size_t)hd * 512 + t) * 64 + d;
                    else             addr = ((size_t)hd * 64 + d) * 512 + t;
                }
                out[addr] = (TO)v;
            }
        }
    }
}

__global__ __launch_bounds__(256) void qkv_kernel(
    const float* __restrict__ qin, const float* __restrict__ kin, const float* __restrict__ vin,
    const float* __restrict__ Wq, const float* __restrict__ Bq,
    const float* __restrict__ Wk, const float* __restrict__ Bk,
    const float* __restrict__ Wv, const float* __restrict__ Bv,
    bf16* __restrict__ Qws, bf16* __restrict__ Kws, bf16* __restrict__ Vtws)
{
    __shared__ bf16 Asm[64][LDA];
    __shared__ bf16 Bsm[64][LDA];
    const int mblk = blockIdx.x * 64;
    const int nblk = blockIdx.y * 64;
    const int z = blockIdx.z;
    floatx4 acc[2][2] = {};
    const float *A, *W, *bias;
    if (z == 0)      { A = qin; W = Wq; bias = Bq; }
    else if (z == 1) { A = kin; W = Wk; bias = Bk; }
    else             { A = vin; W = Wv; bias = Bv; }
    gemm_tile(A, W, Asm, Bsm, acc, mblk, nblk);
    if (z == 0)      gemm_epilogue<0, bf16>(bias, Qws,  acc, mblk, nblk);
    else if (z == 1) gemm_epilogue<0, bf16>(bias, Kws,  acc, mblk, nblk);
    else             gemm_epilogue<1, bf16>(bias, Vtws, acc, mblk, nblk);
}

__global__ __launch_bounds__(256) void out_kernel(
    const bf16* __restrict__ X, const float* __restrict__ Wo,
    const float* __restrict__ Bo, float* __restrict__ out)
{
    __shared__ bf16 Asm[64][LDA];
    __shared__ bf16 Bsm[64][LDA];
    const int mblk = blockIdx.x * 64;
    const int nblk = blockIdx.y * 64;
    floatx4 acc[2][2] = {};
    gemm_tile(X, Wo, Asm, Bsm, acc, mblk, nblk);
    gemm_epilogue<2, float>(Bo, out, acc, mblk, nblk);
}

// ---------------- attention: one block = one head x 16 queries ----------------
#define SST 520  // S stride (fp32)
#define PST 520  // P stride (bf16): rows 1040B, 16B aligned

__global__ __launch_bounds__(256) void attn_kernel(
    const bf16* __restrict__ Qws, const bf16* __restrict__ Kws,
    const bf16* __restrict__ Vtws, const int* __restrict__ mask,
    bf16* __restrict__ Xws)
{
    __shared__ float Ssm[16][SST];
    __shared__ bf16  Psm[16][PST];
    const int tid  = threadIdx.x;
    const int wave = tid >> 6;
    const int lane = tid & 63;
    const int quad = lane >> 4;
    const int l16  = lane & 15;
    const int qt = blockIdx.x;   // 0..31 (16 queries each)
    const int hd = blockIdx.y;   // 0..127
    const int q0 = qt * 16;
    const int b = hd >> 6;
    const int h = (hd >> 3) & 7;
    const int c = hd & 7;

    // ---- phase 1: S = Q K^T / 8 ; wave w handles keys [w*128, w*128+128)
    const bf16* Qh = Qws + (size_t)hd * 512 * 64;
    const bf16* Kh = Kws + (size_t)hd * 512 * 64;
    bf16x8 aq0 = *(const bf16x8*)(Qh + (size_t)(q0 + l16) * 64 + quad * 8);
    bf16x8 aq1 = *(const bf16x8*)(Qh + (size_t)(q0 + l16) * 64 + 32 + quad * 8);
    #pragma unroll
    for (int nt = 0; nt < 8; nt++) {
        const int s0 = wave * 128 + nt * 16;
        bf16x8 bk0 = *(const bf16x8*)(Kh + (size_t)(s0 + l16) * 64 + quad * 8);
        bf16x8 bk1 = *(const bf16x8*)(Kh + (size_t)(s0 + l16) * 64 + 32 + quad * 8);
        floatx4 s = {};
        s = __builtin_amdgcn_mfma_f32_16x16x32_bf16(aq0, bk0, s, 0, 0, 0);
        s = __builtin_amdgcn_mfma_f32_16x16x32_bf16(aq1, bk1, s, 0, 0, 0);
        #pragma unroll
        for (int r = 0; r < 4; r++)
            Ssm[quad * 4 + r][s0 + l16] = s[r] * 0.125f;
    }
    __syncthreads();

    // ---- softmax over 512 keys; row = tid>>4, thread covers cols i0+16*jj
    {
        const int row = tid >> 4;
        const int i0  = tid & 15;
        const int t   = q0 + row;
        const int* mrow = mask + ((size_t)b * 512 + t) * 512;
        float sv[32];
        float mx = -3.0e38f;
        #pragma unroll
        for (int jj = 0; jj < 32; jj++) {
            const int col = i0 + 16 * jj;
            float s = Ssm[row][col];
            if (mrow[col] == 0) s = -1.0e9f;
            sv[jj] = s;
            mx = fmaxf(mx, s);
        }
        #pragma unroll
        for (int off = 1; off < 16; off <<= 1) mx = fmaxf(mx, __shfl_xor(mx, off, 64));
        float sum = 0.f;
        #pragma unroll
        for (int jj = 0; jj < 32; jj++) { float e = __expf(sv[jj] - mx); sv[jj] = e; sum += e; }
        #pragma unroll
        for (int off = 1; off < 16; off <<= 1) sum += __shfl_xor(sum, off, 64);
        const float inv = 1.f / sum;
        #pragma unroll
        for (int jj = 0; jj < 32; jj++)
            Psm[row][i0 + 16 * jj] = (bf16)(sv[jj] * inv);
    }
    __syncthreads();

    // ---- phase 2: X_tile = P @ V ; wave w computes d-range [w*16, w*16+16)
    const bf16* Vh = Vtws + (size_t)hd * 64 * 512;  // [d][t]
    const int d0 = wave * 16;
    floatx4 o = {};
    #pragma unroll
    for (int ks = 0; ks < 16; ks++) {
        bf16x8 ap = *(const bf16x8*)(&Psm[l16][ks * 32 + quad * 8]);
        bf16x8 bv = *(const bf16x8*)(Vh + (size_t)(d0 + l16) * 512 + ks * 32 + quad * 8);
        o = __builtin_amdgcn_mfma_f32_16x16x32_bf16(ap, bv, o, 0, 0, 0);
    }
    #pragma unroll
    for (int r = 0; r < 4; r++) {
        const int q = quad * 4 + r;
        const size_t row = ((size_t)b * 512 + q0 + q) * 8 + c;
        Xws[row * 512 + h * 64 + d0 + l16] = (bf16)o[r];
    }
}

extern "C" void kernel_launch(void* const* d_in, const int* in_sizes, int n_in,
                              void* d_out, int out_size, void* d_ws, size_t ws_size,
                              hipStream_t stream)
{
    const float* qin  = (const float*)d_in[0];
    const float* kin  = (const float*)d_in[1];
    const float* vin  = (const float*)d_in[2];
    const int*   mask = (const int*)d_in[3];
    const float* Wq = (const float*)d_in[4];
    const float* Bq = (const float*)d_in[5];
    const float* Wk = (const float*)d_in[6];
    const float* Bk = (const float*)d_in[7];
    const float* Wv = (const float*)d_in[8];
    const float* Bv = (const float*)d_in[9];
    const float* Wo = (const float*)d_in[10];
    const float* Bo = (const float*)d_in[11];
    float* out = (float*)d_out;

    // ws: Q | K | V^T | X, each 8192*512 bf16 (8.39 MB) => 33.6 MB
    // (round 2 ran with this footprint -> ws_size admits it).
    bf16* Qws  = (bf16*)d_ws;
    bf16* Kws  = Qws  + (size_t)8192 * 512;
    bf16* Vtws = Kws  + (size_t)8192 * 512;
    bf16* Xws  = Vtws + (size_t)8192 * 512;

    qkv_kernel<<<dim3(128, 8, 3), dim3(256), 0, stream>>>(
        qin, kin, vin, Wq, Bq, Wk, Bk, Wv, Bv, Qws, Kws, Vtws);
    attn_kernel<<<dim3(32, 128), dim3(256), 0, stream>>>(
        Qws, Kws, Vtws, mask, Xws);
    out_kernel<<<dim3(128, 8), dim3(256), 0, stream>>>(
        Xws, Wo, Bo, out);
}